// Round 5
// baseline (153.835 us; speedup 1.0000x reference)
//
#include <hip/hip_runtime.h>

#define IMG 256
#define NB 64
#define NCH 8
#define NROWS (NB * IMG)   // 16384 (b,h) rows
#define PLANE (IMG * IMG)  // 65536

typedef float vf4 __attribute__((ext_vector_type(4)));
typedef float vf2 __attribute__((ext_vector_type(2)));

// floor(sqrt(x)) for 0 <= x <= 65535, exact via f32 sqrt + +/-1 correction
__device__ __forceinline__ int isqrt_i(int x) {
    int t = (int)__builtin_sqrtf((float)x);
    t -= (t * t > x);
    t += ((t + 1) * (t + 1) <= x);
    return t;
}

// Closed-form row interval count. mask(b,h,w) <=> (2w-255)^2 + (2h-255)^2 < s^2
// (exact integer equivalence with the reference's f32 sqrt comparison).
// cnt is even; interval is [lo, 255-lo] with lo = (255 - (cnt-1))/2.
__device__ __forceinline__ int row_count(int s, int h) {
    int ky = 2 * h - 255;
    int rem = s * s - ky * ky;
    if (rem < 2) return 0;             // need kx^2 < rem with kx odd >= 1
    int t = isqrt_i(rem - 1);          // largest t with t^2 < rem
    int kx_max = (t & 1) ? t : t - 1;  // kx = 255-2w is odd
    return kx_max + 1;
}

// Setup: one block, 1024 threads. Thread t handles image b=t>>4, rows
// [16*(t&15), +16). Computes rowinfo[row] = {n0, lo | cnt<<16} via a
// segmented wave scan (16-thread groups = one image) + 64-wide image scan.
__global__ void setup_kernel(const int* __restrict__ sizes,
                             int2* __restrict__ rowinfo,
                             float* __restrict__ out, int out_size) {
    __shared__ int tot[NB];
    __shared__ int ibase[NB];
    int t = threadIdx.x;          // 0..1023
    int lane = t & 63;
    int b = t >> 4;
    int h0 = (t & 15) * 16;
    int s = sizes[b];

    int c[16];
    int chunksum = 0;
    #pragma unroll
    for (int k = 0; k < 16; ++k) { c[k] = row_count(s, h0 + k); chunksum += c[k]; }

    // segmented inclusive scan within 16-lane groups (one image per group)
    int v = chunksum;
    #pragma unroll
    for (int d = 1; d < 16; d <<= 1) {
        int u = __shfl_up(v, d);
        if ((lane & 15) >= d) v += u;
    }
    if ((t & 15) == 15) tot[b] = v;   // image total
    __syncthreads();
    if (t < NB) {
        int a = tot[t];
        int iv = a;
        #pragma unroll
        for (int d = 1; d < NB; d <<= 1) {
            int u = __shfl_up(iv, d);
            if (t >= d) iv += u;
        }
        ibase[t] = iv - a;            // exclusive image base
    }
    __syncthreads();

    int n0 = ibase[b] + (v - chunksum);   // exclusive within image
    #pragma unroll
    for (int k = 0; k < 16; ++k) {
        int cnt = c[k];
        int lo = (cnt > 0) ? ((255 - (cnt - 1)) >> 1) : 0;
        rowinfo[b * IMG + h0 + k] = make_int2(n0, lo | (cnt << 16));
        n0 += cnt;
    }
    if (t == 0) out[out_size - 1] = (float)NB;  // batch_size = 64
}

// Scatter: 4096 blocks x 256 threads; wave = one row, thread = 4 pixels.
// Pure streaming: 8x vf4 NT loads, transpose-in-register, NT stores.
__global__ void __launch_bounds__(256) scatter_rows(
        const float* __restrict__ batch,
        const int2* __restrict__ rowinfo,
        float* __restrict__ out, int N) {
    int wid = threadIdx.x >> 6;
    int lane = threadIdx.x & 63;
    int row = blockIdx.x * 4 + wid;
    int2 ri = rowinfo[row];           // wave-uniform -> s_load
    int lo = ri.y & 0xffff;
    int cnt = ri.y >> 16;
    if (cnt == 0) return;             // wave-uniform exit
    int hi = lo + cnt;
    int w0 = lane * 4;
    if (w0 >= hi || w0 + 3 < lo) return;

    int b = row >> 8;
    int h = row & 255;
    int n0 = ri.x;

    const float* bp = batch + (size_t)b * NCH * PLANE + h * IMG + w0;
    vf4 v[NCH];
    #pragma unroll
    for (int ch = 0; ch < NCH; ++ch)
        v[ch] = __builtin_nontemporal_load((const vf4*)(bp + ch * PLANE));

    float* texs = out;
    float* ptss = out + (size_t)N * 8;
    float* imgs = out + (size_t)N * 10;
    float fh = (float)h;
    float fb = (float)b;

    #pragma unroll
    for (int j = 0; j < 4; ++j) {
        int w = w0 + j;
        if (w < lo || w >= hi) continue;
        int n = n0 + (w - lo);
        vf4 t0, t1;
        t0.x = v[0][j]; t0.y = v[1][j]; t0.z = v[2][j]; t0.w = v[3][j];
        t1.x = v[4][j]; t1.y = v[5][j]; t1.z = v[6][j]; t1.w = v[7][j];
        __builtin_nontemporal_store(t0, (vf4*)(texs + (size_t)n * 8));
        __builtin_nontemporal_store(t1, (vf4*)(texs + (size_t)n * 8 + 4));
        vf2 p; p.x = fh; p.y = (float)w;
        __builtin_nontemporal_store(p, (vf2*)(ptss + (size_t)n * 2));
        __builtin_nontemporal_store(fb, imgs + n);
    }
}

extern "C" void kernel_launch(void* const* d_in, const int* in_sizes, int n_in,
                              void* d_out, int out_size, void* d_ws, size_t ws_size,
                              hipStream_t stream) {
    const float* batch = (const float*)d_in[0];
    const int* sizes = (const int*)d_in[1];
    float* out = (float*)d_out;

    // out layout: tex [N*8] | pts [N*2] | imgid [N] | batch_size [1]
    int N = (out_size - 1) / 11;

    int2* rowinfo = (int2*)d_ws;   // 16384 * 8B = 128 KB

    setup_kernel<<<1, 1024, 0, stream>>>(sizes, rowinfo, out, out_size);
    scatter_rows<<<NROWS / 4, 256, 0, stream>>>(batch, rowinfo, out, N);
}

// Round 6
// 44.763 us; speedup vs baseline: 3.4366x; 3.4366x over previous
//
#include <hip/hip_runtime.h>

#define IMG 256
#define NB 64
#define NCH 8
#define NROWS (NB * IMG)   // 16384 (b,h) rows
#define PLANE (IMG * IMG)  // 65536

typedef float vf4 __attribute__((ext_vector_type(4)));
typedef float vf2 __attribute__((ext_vector_type(2)));

// floor(sqrt(x)) for 0 <= x <= 65535, exact via f32 sqrt + +/-1 correction
__device__ __forceinline__ int isqrt_i(int x) {
    int t = (int)__builtin_sqrtf((float)x);
    t -= (t * t > x);
    t += ((t + 1) * (t + 1) <= x);
    return t;
}

// Closed-form row interval count. mask(b,h,w) <=> (2w-255)^2 + (2h-255)^2 < s^2
// (exact integer equivalence with the reference's f32 sqrt comparison).
// cnt is even; interval is [lo, 255-lo] with lo = (255 - (cnt-1))/2.
__device__ __forceinline__ int row_count(int s, int h) {
    int ky = 2 * h - 255;
    int rem = s * s - ky * ky;
    if (rem < 2) return 0;             // need kx^2 < rem with kx odd >= 1
    int t = isqrt_i(rem - 1);          // largest t with t^2 < rem
    int kx_max = (t & 1) ? t : t - 1;  // kx = 255-2w is odd
    return kx_max + 1;
}

// Setup: one block, 1024 threads. Thread t handles image b=t>>4, rows
// [16*(t&15), +16). Computes rowinfo[row] = {n0, lo | cnt<<16} via a
// segmented wave scan (16-thread groups = one image) + 64-wide image scan.
__global__ void setup_kernel(const int* __restrict__ sizes,
                             int2* __restrict__ rowinfo,
                             float* __restrict__ out, int out_size) {
    __shared__ int tot[NB];
    __shared__ int ibase[NB];
    int t = threadIdx.x;          // 0..1023
    int lane = t & 63;
    int b = t >> 4;
    int h0 = (t & 15) * 16;
    int s = sizes[b];

    int c[16];
    int chunksum = 0;
    #pragma unroll
    for (int k = 0; k < 16; ++k) { c[k] = row_count(s, h0 + k); chunksum += c[k]; }

    // segmented inclusive scan within 16-lane groups (one image per group)
    int v = chunksum;
    #pragma unroll
    for (int d = 1; d < 16; d <<= 1) {
        int u = __shfl_up(v, d);
        if ((lane & 15) >= d) v += u;
    }
    if ((t & 15) == 15) tot[b] = v;   // image total
    __syncthreads();
    if (t < NB) {
        int a = tot[t];
        int iv = a;
        #pragma unroll
        for (int d = 1; d < NB; d <<= 1) {
            int u = __shfl_up(iv, d);
            if (t >= d) iv += u;
        }
        ibase[t] = iv - a;            // exclusive image base
    }
    __syncthreads();

    int n0 = ibase[b] + (v - chunksum);   // exclusive within image
    #pragma unroll
    for (int k = 0; k < 16; ++k) {
        int cnt = c[k];
        int lo = (cnt > 0) ? ((255 - (cnt - 1)) >> 1) : 0;
        rowinfo[b * IMG + h0 + k] = make_int2(n0, lo | (cnt << 16));
        n0 += cnt;
    }
    if (t == 0) out[out_size - 1] = (float)NB;  // batch_size = 64
}

// Scatter: 4096 blocks x 256 threads; wave = one row, thread = 4 pixels.
// 8x vf4 loads, transpose-in-register, regular caching stores (L2 merges
// the 32B-per-point pattern into full lines; NT stores caused 2.8x write
// amplification in R5 -- do not reintroduce).
__global__ void __launch_bounds__(256) scatter_rows(
        const float* __restrict__ batch,
        const int2* __restrict__ rowinfo,
        float* __restrict__ out, int N) {
    int wid = threadIdx.x >> 6;
    int lane = threadIdx.x & 63;
    int row = blockIdx.x * 4 + wid;
    int2 ri = rowinfo[row];           // wave-uniform -> s_load
    int lo = ri.y & 0xffff;
    int cnt = ri.y >> 16;
    if (cnt == 0) return;             // wave-uniform exit
    int hi = lo + cnt;
    int w0 = lane * 4;
    if (w0 >= hi || w0 + 3 < lo) return;

    int b = row >> 8;
    int h = row & 255;
    int n0 = ri.x;

    const float* bp = batch + (size_t)b * NCH * PLANE + h * IMG + w0;
    vf4 v[NCH];
    #pragma unroll
    for (int ch = 0; ch < NCH; ++ch)
        v[ch] = *(const vf4*)(bp + ch * PLANE);

    float* texs = out;
    float* ptss = out + (size_t)N * 8;
    float* imgs = out + (size_t)N * 10;
    float fh = (float)h;
    float fb = (float)b;

    #pragma unroll
    for (int j = 0; j < 4; ++j) {
        int w = w0 + j;
        if (w < lo || w >= hi) continue;
        int n = n0 + (w - lo);
        vf4 t0, t1;
        t0.x = v[0][j]; t0.y = v[1][j]; t0.z = v[2][j]; t0.w = v[3][j];
        t1.x = v[4][j]; t1.y = v[5][j]; t1.z = v[6][j]; t1.w = v[7][j];
        *(vf4*)(texs + (size_t)n * 8) = t0;
        *(vf4*)(texs + (size_t)n * 8 + 4) = t1;
        vf2 p; p.x = fh; p.y = (float)w;
        *(vf2*)(ptss + (size_t)n * 2) = p;
        imgs[n] = fb;
    }
}

extern "C" void kernel_launch(void* const* d_in, const int* in_sizes, int n_in,
                              void* d_out, int out_size, void* d_ws, size_t ws_size,
                              hipStream_t stream) {
    const float* batch = (const float*)d_in[0];
    const int* sizes = (const int*)d_in[1];
    float* out = (float*)d_out;

    // out layout: tex [N*8] | pts [N*2] | imgid [N] | batch_size [1]
    int N = (out_size - 1) / 11;

    int2* rowinfo = (int2*)d_ws;   // 16384 * 8B = 128 KB

    setup_kernel<<<1, 1024, 0, stream>>>(sizes, rowinfo, out, out_size);
    scatter_rows<<<NROWS / 4, 256, 0, stream>>>(batch, rowinfo, out, N);
}

// Round 7
// 38.790 us; speedup vs baseline: 3.9658x; 1.1540x over previous
//
#include <hip/hip_runtime.h>

#define IMG 256
#define NB 64
#define NCH 8
#define NROWS (NB * IMG)   // 16384 (b,h) rows
#define PLANE (IMG * IMG)  // 65536

typedef float vf4 __attribute__((ext_vector_type(4)));
typedef float vf2 __attribute__((ext_vector_type(2)));

// floor(sqrt(x)) for 0 <= x <= 65535, exact via f32 sqrt + +/-1 correction
__device__ __forceinline__ int isqrt_i(int x) {
    int t = (int)__builtin_sqrtf((float)x);
    t -= (t * t > x);
    t += ((t + 1) * (t + 1) <= x);
    return t;
}

// Closed-form row interval count. mask(b,h,w) <=> (2w-255)^2 + (2h-255)^2 < s^2
// (exact integer equivalence with the reference's f32 sqrt comparison).
// cnt is even; interval is [lo, 255-lo] with lo = (255 - (cnt-1))/2.
__device__ __forceinline__ int row_count(int s, int h) {
    int ky = 2 * h - 255;
    int rem = s * s - ky * ky;
    if (rem < 2) return 0;             // need kx^2 < rem with kx odd >= 1
    int t = isqrt_i(rem - 1);          // largest t with t^2 < rem
    int kx_max = (t & 1) ? t : t - 1;  // kx = 255-2w is odd
    return kx_max + 1;
}

// Setup: one block, 1024 threads. rowinfo[row] = {n0 (global prefix), lo|cnt<<16}.
// n0 is monotone non-decreasing (empty rows carry the running value), which the
// scatter's binary search relies on.
__global__ void setup_kernel(const int* __restrict__ sizes,
                             int2* __restrict__ rowinfo,
                             float* __restrict__ out, int out_size) {
    __shared__ int tot[NB];
    __shared__ int ibase[NB];
    int t = threadIdx.x;          // 0..1023
    int lane = t & 63;
    int b = t >> 4;
    int h0 = (t & 15) * 16;
    int s = sizes[b];

    int c[16];
    int chunksum = 0;
    #pragma unroll
    for (int k = 0; k < 16; ++k) { c[k] = row_count(s, h0 + k); chunksum += c[k]; }

    // segmented inclusive scan within 16-lane groups (one image per group)
    int v = chunksum;
    #pragma unroll
    for (int d = 1; d < 16; d <<= 1) {
        int u = __shfl_up(v, d);
        if ((lane & 15) >= d) v += u;
    }
    if ((t & 15) == 15) tot[b] = v;   // image total
    __syncthreads();
    if (t < NB) {
        int a = tot[t];
        int iv = a;
        #pragma unroll
        for (int d = 1; d < NB; d <<= 1) {
            int u = __shfl_up(iv, d);
            if (t >= d) iv += u;
        }
        ibase[t] = iv - a;            // exclusive image base
    }
    __syncthreads();

    int n0 = ibase[b] + (v - chunksum);   // global exclusive prefix
    #pragma unroll
    for (int k = 0; k < 16; ++k) {
        int cnt = c[k];
        int lo = (cnt > 0) ? ((255 - (cnt - 1)) >> 1) : 0;
        rowinfo[b * IMG + h0 + k] = make_int2(n0, lo | (cnt << 16));
        n0 += cnt;
    }
    if (t == 0) out[out_size - 1] = (float)NB;  // batch_size = 64
}

// Scatter: thread = one output point n. Binary search rowinfo[].x (prefix) for
// the containing row (largest row with n0 <= n; empty rows share n0 with their
// successor so the largest match is always non-empty). Fully dense lanes.
__global__ void __launch_bounds__(256) scatter_points(
        const float* __restrict__ batch,
        const int2* __restrict__ rowinfo,
        float* __restrict__ out, int N) {
    int n = blockIdx.x * 256 + threadIdx.x;
    if (n >= N) return;

    int lo_i = 0, hi_i = NROWS;   // invariant: start[lo_i] <= n < start[hi_i]
    #pragma unroll
    for (int it = 0; it < 14; ++it) {
        int mid = (lo_i + hi_i) >> 1;
        int sm = rowinfo[mid].x;
        if (sm <= n) lo_i = mid; else hi_i = mid;
    }
    int row = lo_i;
    int2 ri = rowinfo[row];
    int b = row >> 8;
    int h = row & 255;
    int lo = ri.y & 0xffff;
    int w = lo + (n - ri.x);

    const float* bp = batch + (size_t)b * NCH * PLANE + h * IMG + w;
    float c0 = bp[0 * PLANE], c1 = bp[1 * PLANE], c2 = bp[2 * PLANE],
          c3 = bp[3 * PLANE], c4 = bp[4 * PLANE], c5 = bp[5 * PLANE],
          c6 = bp[6 * PLANE], c7 = bp[7 * PLANE];

    vf4 t0, t1;
    t0.x = c0; t0.y = c1; t0.z = c2; t0.w = c3;
    t1.x = c4; t1.y = c5; t1.z = c6; t1.w = c7;
    *(vf4*)(out + (size_t)n * 8) = t0;
    *(vf4*)(out + (size_t)n * 8 + 4) = t1;

    vf2 p; p.x = (float)h; p.y = (float)w;
    *(vf2*)(out + (size_t)N * 8 + (size_t)n * 2) = p;

    out[(size_t)N * 10 + n] = (float)b;
}

extern "C" void kernel_launch(void* const* d_in, const int* in_sizes, int n_in,
                              void* d_out, int out_size, void* d_ws, size_t ws_size,
                              hipStream_t stream) {
    const float* batch = (const float*)d_in[0];
    const int* sizes = (const int*)d_in[1];
    float* out = (float*)d_out;

    // out layout: tex [N*8] | pts [N*2] | imgid [N] | batch_size [1]
    int N = (out_size - 1) / 11;

    int2* rowinfo = (int2*)d_ws;   // 16384 * 8B = 128 KB

    setup_kernel<<<1, 1024, 0, stream>>>(sizes, rowinfo, out, out_size);
    scatter_points<<<(N + 255) / 256, 256, 0, stream>>>(batch, rowinfo, out, N);
}

// Round 8
// 35.737 us; speedup vs baseline: 4.3046x; 1.0854x over previous
//
#include <hip/hip_runtime.h>

#define IMG 256
#define NB 64
#define NCH 8
#define NROWS (NB * IMG)   // 16384 (b,h) rows
#define PLANE (IMG * IMG)  // 65536
#define SCAT_BLOCKS 2048   // persistent blocks; 8 rows each

typedef float vf4 __attribute__((ext_vector_type(4)));
typedef float vf2 __attribute__((ext_vector_type(2)));

// floor(sqrt(x)) for 0 <= x <= 65535, exact via f32 sqrt + +/-1 correction
__device__ __forceinline__ int isqrt_i(int x) {
    int t = (int)__builtin_sqrtf((float)x);
    t -= (t * t > x);
    t += ((t + 1) * (t + 1) <= x);
    return t;
}

// Closed-form row interval count. mask(b,h,w) <=> (2w-255)^2 + (2h-255)^2 < s^2
// (exact integer equivalence with the reference's f32 sqrt comparison).
// cnt is even; interval is [lo, 255-lo] with lo = (255 - (cnt-1))/2.
__device__ __forceinline__ int row_count(int s, int h) {
    int ky = 2 * h - 255;
    int rem = s * s - ky * ky;
    if (rem < 2) return 0;             // need kx^2 < rem with kx odd >= 1
    int t = isqrt_i(rem - 1);          // largest t with t^2 < rem
    int kx_max = (t & 1) ? t : t - 1;  // kx = 255-2w is odd
    return kx_max + 1;
}

// Setup: one block, 1024 threads. rowinfo[row] = {n0 (global prefix), lo|cnt<<16}.
__global__ void setup_kernel(const int* __restrict__ sizes,
                             int2* __restrict__ rowinfo,
                             float* __restrict__ out, int out_size) {
    __shared__ int tot[NB];
    __shared__ int ibase[NB];
    int t = threadIdx.x;          // 0..1023
    int lane = t & 63;
    int b = t >> 4;
    int h0 = (t & 15) * 16;
    int s = sizes[b];

    int c[16];
    int chunksum = 0;
    #pragma unroll
    for (int k = 0; k < 16; ++k) { c[k] = row_count(s, h0 + k); chunksum += c[k]; }

    // segmented inclusive scan within 16-lane groups (one image per group)
    int v = chunksum;
    #pragma unroll
    for (int d = 1; d < 16; d <<= 1) {
        int u = __shfl_up(v, d);
        if ((lane & 15) >= d) v += u;
    }
    if ((t & 15) == 15) tot[b] = v;   // image total
    __syncthreads();
    if (t < NB) {
        int a = tot[t];
        int iv = a;
        #pragma unroll
        for (int d = 1; d < NB; d <<= 1) {
            int u = __shfl_up(iv, d);
            if (t >= d) iv += u;
        }
        ibase[t] = iv - a;            // exclusive image base
    }
    __syncthreads();

    int n0 = ibase[b] + (v - chunksum);   // global exclusive prefix
    #pragma unroll
    for (int k = 0; k < 16; ++k) {
        int cnt = c[k];
        int lo = (cnt > 0) ? ((255 - (cnt - 1)) >> 1) : 0;
        rowinfo[b * IMG + h0 + k] = make_int2(n0, lo | (cnt << 16));
        n0 += cnt;
    }
    if (t == 0) out[out_size - 1] = (float)NB;  // batch_size = 64
}

// Scatter: persistent grid-stride over rows. Per row iteration: R3's proven
// pattern (thread = w, 8 scalar channel loads, 2x vf4 + vf2 + dword stores).
__global__ void __launch_bounds__(256) scatter_rows(
        const float* __restrict__ batch,
        const int2* __restrict__ rowinfo,
        float* __restrict__ out, int N) {
    int t = threadIdx.x;
    float* texs = out;
    float* ptss = out + (size_t)N * 8;
    float* imgs = out + (size_t)N * 10;

    for (int row = blockIdx.x; row < NROWS; row += SCAT_BLOCKS) {
        int2 ri = rowinfo[row];       // wave-uniform
        int cnt = ri.y >> 16;
        if (cnt == 0) continue;       // uniform skip
        int lo = ri.y & 0xffff;
        if (t < lo || t >= lo + cnt) continue;

        int b = row >> 8;
        int h = row & 255;
        int n = ri.x + (t - lo);

        const float* bp = batch + (size_t)b * NCH * PLANE + h * IMG + t;
        float c0 = bp[0 * PLANE], c1 = bp[1 * PLANE], c2 = bp[2 * PLANE],
              c3 = bp[3 * PLANE], c4 = bp[4 * PLANE], c5 = bp[5 * PLANE],
              c6 = bp[6 * PLANE], c7 = bp[7 * PLANE];

        vf4 t0, t1;
        t0.x = c0; t0.y = c1; t0.z = c2; t0.w = c3;
        t1.x = c4; t1.y = c5; t1.z = c6; t1.w = c7;
        *(vf4*)(texs + (size_t)n * 8) = t0;
        *(vf4*)(texs + (size_t)n * 8 + 4) = t1;

        vf2 p; p.x = (float)h; p.y = (float)t;
        *(vf2*)(ptss + (size_t)n * 2) = p;

        imgs[n] = (float)b;
    }
}

extern "C" void kernel_launch(void* const* d_in, const int* in_sizes, int n_in,
                              void* d_out, int out_size, void* d_ws, size_t ws_size,
                              hipStream_t stream) {
    const float* batch = (const float*)d_in[0];
    const int* sizes = (const int*)d_in[1];
    float* out = (float*)d_out;

    // out layout: tex [N*8] | pts [N*2] | imgid [N] | batch_size [1]
    int N = (out_size - 1) / 11;

    int2* rowinfo = (int2*)d_ws;   // 16384 * 8B = 128 KB

    setup_kernel<<<1, 1024, 0, stream>>>(sizes, rowinfo, out, out_size);
    scatter_rows<<<SCAT_BLOCKS, 256, 0, stream>>>(batch, rowinfo, out, N);
}